// Round 11
// baseline (495.878 us; speedup 1.0000x reference)
//
#include <hip/hip_runtime.h>

#define BB 4
#define SS 1024
#define DD 512
#define HH 16
#define DH 32

typedef __attribute__((ext_vector_type(8))) short bf16x8;
typedef __attribute__((ext_vector_type(4))) float f32x4;

__device__ __forceinline__ short f2bf(float x) {
    union { float f; unsigned u; } v; v.f = x;
    unsigned r = (v.u + 0x7FFFu + ((v.u >> 16) & 1u)) >> 16;
    return (short)r;
}
__device__ __forceinline__ float bf2f(unsigned short u) {
    union { unsigned u; float f; } v; v.u = ((unsigned)u) << 16;
    return v.f;
}
__device__ __forceinline__ void gl_lds16(const void* g, void* l) {
    __builtin_amdgcn_global_load_lds(
        (const __attribute__((address_space(1))) unsigned int*)g,
        (__attribute__((address_space(3))) unsigned int*)l, 16, 0, 0);
}

// ---------------------------------------------------------------------------
// Preprocessing: 5 weight transposes (fp32 -> bf16 WT[n][k]=W[k][n]) + mask
// normalized to BYTES.
// ---------------------------------------------------------------------------
__global__ __launch_bounds__(256) void prep_kernel(
    const float* __restrict__ Wq, const float* __restrict__ Wk,
    const float* __restrict__ Wv, const float* __restrict__ Wp,
    const float* __restrict__ Wo,
    const unsigned char* __restrict__ mask_raw,
    unsigned short* __restrict__ WqT, unsigned short* __restrict__ WkT,
    unsigned short* __restrict__ WvT, unsigned short* __restrict__ WpT,
    unsigned short* __restrict__ WoT,
    unsigned char* __restrict__ mbyte) {
    __shared__ float t[64][68];
    __shared__ int bad;
    const int bid = blockIdx.x;
    const int tid = threadIdx.x;
    if (bid < 320) {
        int wsel = bid >> 6;
        const float* W; unsigned short* WT;
        if (wsel == 0)      { W = Wq; WT = WqT; }
        else if (wsel == 1) { W = Wk; WT = WkT; }
        else if (wsel == 2) { W = Wv; WT = WvT; }
        else if (wsel == 3) { W = Wp; WT = WpT; }
        else                { W = Wo; WT = WoT; }
        int idx = bid & 63;
        const int bx = (idx >> 3) * 64, by = (idx & 7) * 64;
        const int r = tid >> 4, c4 = (tid & 15) * 4;
#pragma unroll
        for (int i = 0; i < 4; ++i) {
            float4 v = *(const float4*)(W + (size_t)(bx + r + i * 16) * 512 + by + c4);
            t[r + i * 16][c4 + 0] = v.x; t[r + i * 16][c4 + 1] = v.y;
            t[r + i * 16][c4 + 2] = v.z; t[r + i * 16][c4 + 3] = v.w;
        }
        __syncthreads();
#pragma unroll
        for (int i = 0; i < 4; ++i) {
            int c = r + i * 16;
            ushort4 o;
            o.x = (unsigned short)f2bf(t[c4 + 0][c]);
            o.y = (unsigned short)f2bf(t[c4 + 1][c]);
            o.z = (unsigned short)f2bf(t[c4 + 2][c]);
            o.w = (unsigned short)f2bf(t[c4 + 3][c]);
            *(ushort4*)(WT + (size_t)(by + c) * 512 + bx + c4) = o;
        }
    } else {
        if (tid == 0) bad = 0;
        __syncthreads();
        const unsigned int* w = (const unsigned int*)mask_raw;
        int isbad = 0;
        for (int i = tid; i < 1024; i += 256)
            if (w[i] > 1u) isbad = 1;
        if (isbad) atomicOr(&bad, 1);
        __syncthreads();
        if (bad) {
            for (int i = tid; i < BB * SS; i += 256)
                mbyte[i] = mask_raw[i] != 0;
        } else {
            const int* wi = (const int*)mask_raw;
            for (int i = tid; i < BB * SS; i += 256)
                mbyte[i] = wi[i] != 0;
        }
    }
}

// ---------------------------------------------------------------------------
// bf16 MFMA GEMM body (128x128 tile, BK=64, XOR swizzle). AF32/BF32 operands
// are fp32 in global, converted to bf16 in-register during staging.
// ---------------------------------------------------------------------------
template <int MODE, bool AF32, bool BF32>
__device__ __forceinline__ void gemm_body(
    const void* __restrict__ Aptr, const void* __restrict__ BTptr,
    const float* __restrict__ bias, void* __restrict__ Cout, int N,
    int m0, int n0, unsigned short* As, unsigned short* Bs) {
    const int tid = threadIdx.x;
    const int w = tid >> 6, lane = tid & 63;
    const int wm = w >> 1, wn = w & 1;
    const int ln = lane & 15, quad = lane >> 4;
    f32x4 acc[4][4] = {};
    for (int k0 = 0; k0 < 512; k0 += 64) {
        __syncthreads();
#pragma unroll
        for (int i = 0; i < 4; ++i) {
            int slot = i * 256 + tid;
            int row = slot >> 3, sl = slot & 7;
            int gsl = sl ^ (row & 7);
            if (AF32) {
                const float* src = (const float*)Aptr +
                    (size_t)(m0 + row) * 512 + k0 + gsl * 8;
                float4 x0 = *(const float4*)src;
                float4 x1 = *(const float4*)(src + 4);
                bf16x8 pk;
                pk[0] = f2bf(x0.x); pk[1] = f2bf(x0.y);
                pk[2] = f2bf(x0.z); pk[3] = f2bf(x0.w);
                pk[4] = f2bf(x1.x); pk[5] = f2bf(x1.y);
                pk[6] = f2bf(x1.z); pk[7] = f2bf(x1.w);
                *(bf16x8*)(As + slot * 8) = pk;
            } else {
                gl_lds16((const unsigned short*)Aptr +
                         (size_t)(m0 + row) * 512 + k0 + gsl * 8, As + slot * 8);
            }
            if (BF32) {
                const float* src = (const float*)BTptr +
                    (size_t)(n0 + row) * 512 + k0 + gsl * 8;
                float4 x0 = *(const float4*)src;
                float4 x1 = *(const float4*)(src + 4);
                bf16x8 pk;
                pk[0] = f2bf(x0.x); pk[1] = f2bf(x0.y);
                pk[2] = f2bf(x0.z); pk[3] = f2bf(x0.w);
                pk[4] = f2bf(x1.x); pk[5] = f2bf(x1.y);
                pk[6] = f2bf(x1.z); pk[7] = f2bf(x1.w);
                *(bf16x8*)(Bs + slot * 8) = pk;
            } else {
                gl_lds16((const unsigned short*)BTptr +
                         (size_t)(n0 + row) * 512 + k0 + gsl * 8, Bs + slot * 8);
            }
        }
        __syncthreads();
#pragma unroll
        for (int kc = 0; kc < 2; ++kc) {
            bf16x8 af[4], bfr[4];
#pragma unroll
            for (int mt = 0; mt < 4; ++mt) {
                int row = wm * 64 + mt * 16 + ln;
                int sl = (kc * 4 + quad) ^ (row & 7);
                af[mt] = *(const bf16x8*)(As + row * 64 + sl * 8);
            }
#pragma unroll
            for (int nt = 0; nt < 4; ++nt) {
                int row = wn * 64 + nt * 16 + ln;
                int sl = (kc * 4 + quad) ^ (row & 7);
                bfr[nt] = *(const bf16x8*)(Bs + row * 64 + sl * 8);
            }
#pragma unroll
            for (int mt = 0; mt < 4; ++mt)
#pragma unroll
                for (int nt = 0; nt < 4; ++nt)
                    acc[mt][nt] = __builtin_amdgcn_mfma_f32_16x16x32_bf16(
                        af[mt], bfr[nt], acc[mt][nt], 0, 0, 0);
        }
    }
#pragma unroll
    for (int mt = 0; mt < 4; ++mt) {
#pragma unroll
        for (int nt = 0; nt < 4; ++nt) {
            int col = n0 + wn * 64 + nt * 16 + ln;
#pragma unroll
            for (int r = 0; r < 4; ++r) {
                int row = m0 + wm * 64 + mt * 16 + quad * 4 + r;
                float v = acc[mt][nt][r];
                if (MODE == 0) {
                    ((float*)Cout)[(size_t)row * N + col] = v + bias[col];
                } else if (MODE == 1) {
                    ((unsigned short*)Cout)[(size_t)row * N + col] =
                        (unsigned short)f2bf(v);
                } else {
                    int hh = row >> 5, dh = row & 31;
                    int bb = col >> 10, si = col & 1023;
                    ((unsigned short*)Cout)[(((size_t)(bb * HH + hh) * 32 + dh) << 10) + si] =
                        (unsigned short)f2bf(v);
                }
            }
        }
    }
}

// Merged Q/K/V/P projection GEMMs with fused fp32->bf16 conversion
__global__ __launch_bounds__(256) void gemm4_kernel(
    const float* __restrict__ query, const unsigned short* __restrict__ WqT,
    const float* __restrict__ bq, float* __restrict__ qprj,
    const float* __restrict__ key, const unsigned short* __restrict__ WkT,
    unsigned short* __restrict__ kprj,
    const unsigned short* __restrict__ WvT, const float* __restrict__ value,
    unsigned short* __restrict__ vT,
    const float* __restrict__ enc, const unsigned short* __restrict__ WpT,
    unsigned short* __restrict__ pprj) {
    __shared__ unsigned short As[128 * 64];
    __shared__ unsigned short Bs[128 * 64];
    const int bid = blockIdx.x;
    if (bid < 128) {
        gemm_body<0, true, false>(query, WqT, bq, qprj, 512,
                                  (bid >> 2) * 128, (bid & 3) * 128, As, Bs);
    } else if (bid < 256) {
        int s = bid - 128;
        gemm_body<1, true, false>(key, WkT, nullptr, kprj, 512,
                                  (s >> 2) * 128, (s & 3) * 128, As, Bs);
    } else if (bid < 384) {
        int s = bid - 256;
        gemm_body<2, false, true>(WvT, value, nullptr, vT, 4096,
                                  (s >> 5) * 128, (s & 31) * 128, As, Bs);
    } else {
        int s = bid - 384;
        gemm_body<1, true, false>(enc, WpT, nullptr, pprj, 512,
                                  (s >> 2) * 128, (s & 3) * 128, As, Bs);
    }
}

// Output projection: ctx(bf16) @ WoT + bo -> fp32 out
__global__ __launch_bounds__(256) void gemm_out_kernel(
    const unsigned short* __restrict__ ctxbf, const unsigned short* __restrict__ WoT,
    const float* __restrict__ bo, float* __restrict__ outp) {
    __shared__ unsigned short As[128 * 64];
    __shared__ unsigned short Bs[128 * 64];
    const int bid = blockIdx.x;
    gemm_body<0, false, false>(ctxbf, WoT, bo, outp, 512,
                               (bid >> 2) * 128, (bid & 3) * 128, As, Bs);
}

// ---------------------------------------------------------------------------
// Fused attention (R11 = best-of-measured consolidation):
//   R6 structure verbatim (fastest fused measured, 180.2 µs): 256 threads,
//   4 waves x 256 cols, separate A/B pos windows, per-chunk K-preload, no
//   manual lgkm drain, TWO-barrier softmax, NT full-line attn stores, XCD
//   swizzle. Plus R8's ctxs-LDS epilogue (16B ctx stores; kills the +84MB
//   ctx write amplification R6 had) and byte-mask loads.
// ---------------------------------------------------------------------------
__global__ __launch_bounds__(256, 4) void fused_attn_kernel(
    const float* __restrict__ qp, const unsigned short* __restrict__ kp,
    const unsigned short* __restrict__ pp, const unsigned short* __restrict__ vT,
    const float* __restrict__ ub, const float* __restrict__ vb,
    const unsigned char* __restrict__ maskb, float* __restrict__ attn,
    unsigned short* __restrict__ ctxbf) {
    // bijective XCD swizzle (4096 % 8 == 0)
    const int n = blockIdx.x + 64 * blockIdx.y + 1024 * blockIdx.z;
    const int swz = (n & 7) * 512 + (n >> 3);
    const int q0 = (swz & 63) * 16;
    const int h = (swz >> 6) & 15;
    const int b = swz >> 10;
    const int tid = threadIdx.x;
    const int w = tid >> 6, lane = tid & 63;
    const int ln = lane & 15, quad = lane >> 4;

    // [0,17408): posb (phase1) then stg (phase2.5+3), [17408,25600): red
    __shared__ __align__(16) unsigned char smem[25600];
    __shared__ float rowred[2][4][16];
    __shared__ unsigned short ctxs[16][32];

    unsigned short* posb = (unsigned short*)(smem + (size_t)w * 2816);

    // ---- phase 1: S^T score tiles into registers ----
    bf16x8 a_c, a_pA, a_pB;
    {
        const float* qrow = qp + ((size_t)(b * SS + q0 + ln)) * DD + h * DH + quad * 8;
        const int qrB = q0 + ln + 1;
        const float* qrowB = qp + ((size_t)(b * SS + qrB)) * DD + h * DH + quad * 8;
#pragma unroll
        for (int j = 0; j < 8; ++j) {
            float uu = ub[h * DH + quad * 8 + j];
            float vv = vb[h * DH + quad * 8 + j];
            float qv = qrow[j];
            a_c[j] = f2bf(qv + uu);
            a_pA[j] = f2bf(qv + vv);
            a_pB[j] = (qrB < SS) ? f2bf(qrowB[j] + vv) : (short)0;
        }
    }
    const unsigned short* pbase = pp + h * DH + quad * 8;
    const int kw = w * 256;
    f32x4 acc_s[16];
#pragma unroll
    for (int c = 0; c < 4; ++c) {
        const int k0 = kw + c * 64;
        // K fragments preloaded: independent of the pos path, latency overlaps
        bf16x8 bk[4];
#pragma unroll
        for (int t = 0; t < 4; ++t)
            bk[t] = *(const bf16x8*)(
                kp + ((size_t)(b * SS + k0 + t * 16 + ln)) * DD + h * DH + quad * 8);
        const bool needA = (k0 <= q0 + 15);
        const bool needB = (k0 + 63 >= q0 + 1);
        if (needA) {
            const int jA0 = k0 - q0 + SS - 16;
#pragma unroll
            for (int t = 0; t < 5; ++t) {
                int j = jA0 + t * 16 + ln;
                bf16x8 bp;
                if ((unsigned)j < (unsigned)SS) {
                    bp = *(const bf16x8*)(pbase + (size_t)j * DD);
                } else {
#pragma unroll
                    for (int jj = 0; jj < 8; ++jj) bp[jj] = (short)0;
                }
                f32x4 acc = {0.f, 0.f, 0.f, 0.f};
                acc = __builtin_amdgcn_mfma_f32_16x16x32_bf16(bp, a_pA, acc, 0, 0, 0);
                ushort4 o;
                o.x = (unsigned short)f2bf(acc[0]);
                o.y = (unsigned short)f2bf(acc[1]);
                o.z = (unsigned short)f2bf(acc[2]);
                o.w = (unsigned short)f2bf(acc[3]);
                *(ushort4*)(posb + ln * 88 + t * 16 + quad * 4) = o;
            }
        }
        if (needB) {
            const int jB0 = k0 - q0 - 17;
#pragma unroll
            for (int t = 0; t < 5; ++t) {
                int j = jB0 + t * 16 + ln;
                bf16x8 bp;
                if ((unsigned)j < (unsigned)SS) {
                    bp = *(const bf16x8*)(pbase + (size_t)j * DD);
                } else {
#pragma unroll
                    for (int jj = 0; jj < 8; ++jj) bp[jj] = (short)0;
                }
                f32x4 acc = {0.f, 0.f, 0.f, 0.f};
                acc = __builtin_amdgcn_mfma_f32_16x16x32_bf16(bp, a_pB, acc, 0, 0, 0);
                ushort4 o;
                o.x = (unsigned short)f2bf(acc[0]);
                o.y = (unsigned short)f2bf(acc[1]);
                o.z = (unsigned short)f2bf(acc[2]);
                o.w = (unsigned short)f2bf(acc[3]);
                *(ushort4*)(posb + 1408 + ln * 88 + t * 16 + quad * 4) = o;
            }
        }
        // no lgkm drain: same-wave DS ops execute in order; compiler inserts
        // precise waits before the posb-read consumers below.
#pragma unroll
        for (int t = 0; t < 4; ++t) {
            f32x4 acc = {0.f, 0.f, 0.f, 0.f};
            acc = __builtin_amdgcn_mfma_f32_16x16x32_bf16(bk[t], a_c, acc, 0, 0, 0);
#pragma unroll
            for (int r = 0; r < 4; ++r) {
                const int kkl = t * 16 + quad * 4 + r;
                const int which = (k0 + kkl <= q0 + ln) ? 0 : 1;
                acc[r] += bf2f(posb[which * 1408 + ln * 88 + (kkl - ln + 15)]);
            }
            acc_s[c * 4 + t] = acc;
        }
    }

    // ---- phase 2: two-barrier softmax (row = ln, lane-local; exact) ----
    const float scale = 0.04419417382415922f;   // 1/sqrt(512)
    const unsigned char* mrow = maskb + ((size_t)b << 10);
    float mx = -3.4e38f;
#pragma unroll
    for (int tt = 0; tt < 16; ++tt) {
        int col = kw + tt * 16 + quad * 4;
        uchar4 mm = *(const uchar4*)(mrow + col);
        float v0 = mm.x ? -1e9f : acc_s[tt][0] * scale;
        float v1 = mm.y ? -1e9f : acc_s[tt][1] * scale;
        float v2 = mm.z ? -1e9f : acc_s[tt][2] * scale;
        float v3 = mm.w ? -1e9f : acc_s[tt][3] * scale;
        acc_s[tt][0] = v0; acc_s[tt][1] = v1;
        acc_s[tt][2] = v2; acc_s[tt][3] = v3;
        mx = fmaxf(mx, fmaxf(fmaxf(v0, v1), fmaxf(v2, v3)));
    }
    mx = fmaxf(mx, __shfl_xor(mx, 16, 64));
    mx = fmaxf(mx, __shfl_xor(mx, 32, 64));
    if (quad == 0) rowred[0][w][ln] = mx;
    __syncthreads();   // all waves past phase 1 (posb dead from here)
    float gm = fmaxf(fmaxf(rowred[0][0][ln], rowred[0][1][ln]),
                     fmaxf(rowred[0][2][ln], rowred[0][3][ln]));
    float sm = 0.f;
#pragma unroll
    for (int tt = 0; tt < 16; ++tt) {
#pragma unroll
        for (int r = 0; r < 4; ++r) {
            float e = __expf(acc_s[tt][r] - gm);
            acc_s[tt][r] = e;
            sm += e;
        }
    }
    sm += __shfl_xor(sm, 16, 64);
    sm += __shfl_xor(sm, 32, 64);
    if (quad == 0) rowred[1][w][ln] = sm;
    __syncthreads();
    float l = rowred[1][0][ln] + rowred[1][1][ln] +
              rowred[1][2][ln] + rowred[1][3][ln];
    float inv = 1.f / l;

    // ---- phase 2.5 + 3: per 64-col sub-chunk, stage fp32 attn in LDS,
    //      wide NT attn stores, MFMA A-frags from the same tile ----
    float* stg = (float*)(smem + (size_t)w * 4352);   // [16][68] fp32
    f32x4 cacc0 = {0.f, 0.f, 0.f, 0.f}, cacc1 = {0.f, 0.f, 0.f, 0.f};
    const size_t vbase = ((size_t)(b * HH + h)) << 15;   // *32*1024
    float* abase = attn + (((size_t)(b * HH + h)) << 20) + (size_t)q0 * SS;
#pragma unroll
    for (int s = 0; s < 4; ++s) {
#pragma unroll
        for (int t = 0; t < 4; ++t) {
            int tt = s * 4 + t;
            float4 o = make_float4(acc_s[tt][0] * inv, acc_s[tt][1] * inv,
                                   acc_s[tt][2] * inv, acc_s[tt][3] * inv);
            *(float4*)&stg[ln * 68 + t * 16 + quad * 4] = o;
        }
        // full-line NT attn stores: 4 rows x 256B contiguous per instruction
#pragma unroll
        for (int i = 0; i < 4; ++i) {
            int row = i * 4 + quad;
            int c4 = ln * 4;
            f32x4 v = *(f32x4*)&stg[row * 68 + c4];
            __builtin_nontemporal_store(
                v, (f32x4*)&abase[(size_t)row * SS + kw + s * 64 + c4]);
        }
#pragma unroll
        for (int cc = 0; cc < 2; ++cc) {
            int coff = cc * 32 + quad * 8;
            float4 pa = *(float4*)&stg[ln * 68 + coff];
            float4 pb = *(float4*)&stg[ln * 68 + coff + 4];
            bf16x8 af;
            af[0] = f2bf(pa.x); af[1] = f2bf(pa.y);
            af[2] = f2bf(pa.z); af[3] = f2bf(pa.w);
            af[4] = f2bf(pb.x); af[5] = f2bf(pb.y);
            af[6] = f2bf(pb.z); af[7] = f2bf(pb.w);
            int k0 = kw + s * 64 + cc * 32;
            bf16x8 v0 = *(const bf16x8*)(vT + vbase + (((size_t)ln) << 10) + k0 + quad * 8);
            bf16x8 v1 = *(const bf16x8*)(vT + vbase + (((size_t)(16 + ln)) << 10) + k0 + quad * 8);
            cacc0 = __builtin_amdgcn_mfma_f32_16x16x32_bf16(af, v0, cacc0, 0, 0, 0);
            cacc1 = __builtin_amdgcn_mfma_f32_16x16x32_bf16(af, v1, cacc1, 0, 0, 0);
        }
    }

    // cross-wave ctx reduce through dedicated red region (disjoint from stg:
    // stg spans [0,17408), red at [17408,25600) — no barrier needed before
    // writes; own-wave LDS ops are in-order)
    f32x4* red = (f32x4*)(smem + 17408);
    red[(w * 2 + 0) * 64 + lane] = cacc0;
    red[(w * 2 + 1) * 64 + lane] = cacc1;
    __syncthreads();
    if (tid < 128) {
        int nt = tid >> 6, l2 = tid & 63;
        f32x4 s4 = red[(0 * 2 + nt) * 64 + l2] + red[(1 * 2 + nt) * 64 + l2] +
                   red[(2 * 2 + nt) * 64 + l2] + red[(3 * 2 + nt) * 64 + l2];
        int qd = l2 >> 4, lc = l2 & 15;
#pragma unroll
        for (int r = 0; r < 4; ++r)
            ctxs[qd * 4 + r][nt * 16 + lc] = (unsigned short)f2bf(s4[r]);
    }
    __syncthreads();
    if (tid < 64) {
        int row = tid >> 2, c8 = (tid & 3) * 8;
        *(bf16x8*)(ctxbf + ((size_t)(b * SS + q0 + row)) * DD + h * DH + c8) =
            *(const bf16x8*)&ctxs[row][c8];
    }
}

// ---------------------------------------------------------------------------
extern "C" void kernel_launch(void* const* d_in, const int* in_sizes, int n_in,
                              void* d_out, int out_size, void* d_ws, size_t ws_size,
                              hipStream_t stream) {
    const float* query = (const float*)d_in[0];
    const float* key   = (const float*)d_in[1];
    const float* value = (const float*)d_in[2];
    const unsigned char* mask_raw = (const unsigned char*)d_in[3];
    const float* enc   = (const float*)d_in[4];
    const float* Wq    = (const float*)d_in[5];
    const float* bq    = (const float*)d_in[6];
    const float* Wk    = (const float*)d_in[7];
    const float* Wv    = (const float*)d_in[8];
    const float* Wp    = (const float*)d_in[9];
    const float* u_b   = (const float*)d_in[10];
    const float* v_b   = (const float*)d_in[11];
    const float* Wo    = (const float*)d_in[12];
    const float* bo    = (const float*)d_in[13];

    char* wsb = (char*)d_ws;
    float*          qprj = (float*)(wsb + 0);                     // 8 MB fp32
    unsigned short* kprj = (unsigned short*)(wsb + 8388608);      // 4 MB bf16
    unsigned short* vT   = (unsigned short*)(wsb + 12582912);     // 4 MB bf16
    unsigned short* pprj = (unsigned short*)(wsb + 16777216);     // 1 MB bf16
    unsigned char*  mbyte= (unsigned char*)(wsb + 17825792);      // 4 KB
    unsigned short* ctxbf= (unsigned short*)(wsb + 17842176);     // 4 MB bf16
    unsigned short* WqT  = (unsigned short*)(wsb + 22036480);     // 512 KB
    unsigned short* WkT  = (unsigned short*)(wsb + 22560768);     // 512 KB
    unsigned short* WvT  = (unsigned short*)(wsb + 23085056);     // 512 KB
    unsigned short* WpT  = (unsigned short*)(wsb + 23609344);     // 512 KB
    unsigned short* WoT  = (unsigned short*)(wsb + 24133632);     // 512 KB

    float* outp = (float*)d_out;                 // (B,S,D)
    float* attn = outp + (size_t)BB * SS * DD;   // (B,H,S,S)

    prep_kernel<<<321, 256, 0, stream>>>(
        Wq, Wk, Wv, Wp, Wo, mask_raw, WqT, WkT, WvT, WpT, WoT, mbyte);

    gemm4_kernel<<<416, 256, 0, stream>>>(
        query, WqT, bq, qprj, key, WkT, kprj, WvT, value, vT, enc, WpT, pprj);

    fused_attn_kernel<<<dim3(SS / 16, HH, BB), 256, 0, stream>>>(
        qprj, kprj, pprj, vT, u_b, v_b, mbyte, attn, ctxbf);

    gemm_out_kernel<<<128, 256, 0, stream>>>(ctxbf, WoT, bo, outp);
}

// Round 12
// 449.171 us; speedup vs baseline: 1.1040x; 1.1040x over previous
//
#include <hip/hip_runtime.h>

#define BB 4
#define SS 1024
#define DD 512
#define HH 16
#define DH 32

typedef __attribute__((ext_vector_type(8))) short bf16x8;
typedef __attribute__((ext_vector_type(4))) float f32x4;

__device__ __forceinline__ short f2bf(float x) {
    union { float f; unsigned u; } v; v.f = x;
    unsigned r = (v.u + 0x7FFFu + ((v.u >> 16) & 1u)) >> 16;
    return (short)r;
}
__device__ __forceinline__ float bf2f(unsigned short u) {
    union { unsigned u; float f; } v; v.u = ((unsigned)u) << 16;
    return v.f;
}
__device__ __forceinline__ void gl_lds16(const void* g, void* l) {
    __builtin_amdgcn_global_load_lds(
        (const __attribute__((address_space(1))) unsigned int*)g,
        (__attribute__((address_space(3))) unsigned int*)l, 16, 0, 0);
}

// ---------------------------------------------------------------------------
// Preprocessing: 5 weight transposes (fp32 -> bf16 WT[n][k]=W[k][n]) + mask
// normalized to BYTES.
// ---------------------------------------------------------------------------
__global__ __launch_bounds__(256) void prep_kernel(
    const float* __restrict__ Wq, const float* __restrict__ Wk,
    const float* __restrict__ Wv, const float* __restrict__ Wp,
    const float* __restrict__ Wo,
    const unsigned char* __restrict__ mask_raw,
    unsigned short* __restrict__ WqT, unsigned short* __restrict__ WkT,
    unsigned short* __restrict__ WvT, unsigned short* __restrict__ WpT,
    unsigned short* __restrict__ WoT,
    unsigned char* __restrict__ mbyte) {
    __shared__ float t[64][68];
    __shared__ int bad;
    const int bid = blockIdx.x;
    const int tid = threadIdx.x;
    if (bid < 320) {
        int wsel = bid >> 6;
        const float* W; unsigned short* WT;
        if (wsel == 0)      { W = Wq; WT = WqT; }
        else if (wsel == 1) { W = Wk; WT = WkT; }
        else if (wsel == 2) { W = Wv; WT = WvT; }
        else if (wsel == 3) { W = Wp; WT = WpT; }
        else                { W = Wo; WT = WoT; }
        int idx = bid & 63;
        const int bx = (idx >> 3) * 64, by = (idx & 7) * 64;
        const int r = tid >> 4, c4 = (tid & 15) * 4;
#pragma unroll
        for (int i = 0; i < 4; ++i) {
            float4 v = *(const float4*)(W + (size_t)(bx + r + i * 16) * 512 + by + c4);
            t[r + i * 16][c4 + 0] = v.x; t[r + i * 16][c4 + 1] = v.y;
            t[r + i * 16][c4 + 2] = v.z; t[r + i * 16][c4 + 3] = v.w;
        }
        __syncthreads();
#pragma unroll
        for (int i = 0; i < 4; ++i) {
            int c = r + i * 16;
            ushort4 o;
            o.x = (unsigned short)f2bf(t[c4 + 0][c]);
            o.y = (unsigned short)f2bf(t[c4 + 1][c]);
            o.z = (unsigned short)f2bf(t[c4 + 2][c]);
            o.w = (unsigned short)f2bf(t[c4 + 3][c]);
            *(ushort4*)(WT + (size_t)(by + c) * 512 + bx + c4) = o;
        }
    } else {
        if (tid == 0) bad = 0;
        __syncthreads();
        const unsigned int* w = (const unsigned int*)mask_raw;
        int isbad = 0;
        for (int i = tid; i < 1024; i += 256)
            if (w[i] > 1u) isbad = 1;
        if (isbad) atomicOr(&bad, 1);
        __syncthreads();
        if (bad) {
            for (int i = tid; i < BB * SS; i += 256)
                mbyte[i] = mask_raw[i] != 0;
        } else {
            const int* wi = (const int*)mask_raw;
            for (int i = tid; i < BB * SS; i += 256)
                mbyte[i] = wi[i] != 0;
        }
    }
}

// ---------------------------------------------------------------------------
// bf16 MFMA GEMM body (128x128 tile, BK=64, XOR swizzle). AF32/BF32 operands
// are fp32 in global, converted to bf16 in-register during staging.
// MODE 0: fp32 + bias; MODE 1: bf16 row-major; MODE 2: bf16 into
// vT[b][h][dh][s]; MODE 3: bf16 into head-major [b][h][s][dh] (for K/P —
// makes fused's 16-row fragment gathers CONTIGUOUS, 8 lines/instr not 16).
// ---------------------------------------------------------------------------
template <int MODE, bool AF32, bool BF32>
__device__ __forceinline__ void gemm_body(
    const void* __restrict__ Aptr, const void* __restrict__ BTptr,
    const float* __restrict__ bias, void* __restrict__ Cout, int N,
    int m0, int n0, unsigned short* As, unsigned short* Bs) {
    const int tid = threadIdx.x;
    const int w = tid >> 6, lane = tid & 63;
    const int wm = w >> 1, wn = w & 1;
    const int ln = lane & 15, quad = lane >> 4;
    f32x4 acc[4][4] = {};
    for (int k0 = 0; k0 < 512; k0 += 64) {
        __syncthreads();
#pragma unroll
        for (int i = 0; i < 4; ++i) {
            int slot = i * 256 + tid;
            int row = slot >> 3, sl = slot & 7;
            int gsl = sl ^ (row & 7);
            if (AF32) {
                const float* src = (const float*)Aptr +
                    (size_t)(m0 + row) * 512 + k0 + gsl * 8;
                float4 x0 = *(const float4*)src;
                float4 x1 = *(const float4*)(src + 4);
                bf16x8 pk;
                pk[0] = f2bf(x0.x); pk[1] = f2bf(x0.y);
                pk[2] = f2bf(x0.z); pk[3] = f2bf(x0.w);
                pk[4] = f2bf(x1.x); pk[5] = f2bf(x1.y);
                pk[6] = f2bf(x1.z); pk[7] = f2bf(x1.w);
                *(bf16x8*)(As + slot * 8) = pk;
            } else {
                gl_lds16((const unsigned short*)Aptr +
                         (size_t)(m0 + row) * 512 + k0 + gsl * 8, As + slot * 8);
            }
            if (BF32) {
                const float* src = (const float*)BTptr +
                    (size_t)(n0 + row) * 512 + k0 + gsl * 8;
                float4 x0 = *(const float4*)src;
                float4 x1 = *(const float4*)(src + 4);
                bf16x8 pk;
                pk[0] = f2bf(x0.x); pk[1] = f2bf(x0.y);
                pk[2] = f2bf(x0.z); pk[3] = f2bf(x0.w);
                pk[4] = f2bf(x1.x); pk[5] = f2bf(x1.y);
                pk[6] = f2bf(x1.z); pk[7] = f2bf(x1.w);
                *(bf16x8*)(Bs + slot * 8) = pk;
            } else {
                gl_lds16((const unsigned short*)BTptr +
                         (size_t)(n0 + row) * 512 + k0 + gsl * 8, Bs + slot * 8);
            }
        }
        __syncthreads();
#pragma unroll
        for (int kc = 0; kc < 2; ++kc) {
            bf16x8 af[4], bfr[4];
#pragma unroll
            for (int mt = 0; mt < 4; ++mt) {
                int row = wm * 64 + mt * 16 + ln;
                int sl = (kc * 4 + quad) ^ (row & 7);
                af[mt] = *(const bf16x8*)(As + row * 64 + sl * 8);
            }
#pragma unroll
            for (int nt = 0; nt < 4; ++nt) {
                int row = wn * 64 + nt * 16 + ln;
                int sl = (kc * 4 + quad) ^ (row & 7);
                bfr[nt] = *(const bf16x8*)(Bs + row * 64 + sl * 8);
            }
#pragma unroll
            for (int mt = 0; mt < 4; ++mt)
#pragma unroll
                for (int nt = 0; nt < 4; ++nt)
                    acc[mt][nt] = __builtin_amdgcn_mfma_f32_16x16x32_bf16(
                        af[mt], bfr[nt], acc[mt][nt], 0, 0, 0);
        }
    }
#pragma unroll
    for (int mt = 0; mt < 4; ++mt) {
#pragma unroll
        for (int nt = 0; nt < 4; ++nt) {
            int col = n0 + wn * 64 + nt * 16 + ln;
#pragma unroll
            for (int r = 0; r < 4; ++r) {
                int row = m0 + wm * 64 + mt * 16 + quad * 4 + r;
                float v = acc[mt][nt][r];
                if (MODE == 0) {
                    ((float*)Cout)[(size_t)row * N + col] = v + bias[col];
                } else if (MODE == 1) {
                    ((unsigned short*)Cout)[(size_t)row * N + col] =
                        (unsigned short)f2bf(v);
                } else if (MODE == 2) {
                    int hh = row >> 5, dh = row & 31;
                    int bb = col >> 10, si = col & 1023;
                    ((unsigned short*)Cout)[(((size_t)(bb * HH + hh) * 32 + dh) << 10) + si] =
                        (unsigned short)f2bf(v);
                } else {
                    // MODE 3: head-major [b][h][s][dh]
                    int hh = col >> 5, dh = col & 31;
                    int bb = row >> 10, si = row & 1023;
                    ((unsigned short*)Cout)[((((size_t)(bb * HH + hh)) << 10) + si) * 32 + dh] =
                        (unsigned short)f2bf(v);
                }
            }
        }
    }
}

// Merged Q/K/V/P projection GEMMs with fused fp32->bf16 conversion.
// K and P outputs now head-major (MODE 3).
__global__ __launch_bounds__(256) void gemm4_kernel(
    const float* __restrict__ query, const unsigned short* __restrict__ WqT,
    const float* __restrict__ bq, float* __restrict__ qprj,
    const float* __restrict__ key, const unsigned short* __restrict__ WkT,
    unsigned short* __restrict__ kprj,
    const unsigned short* __restrict__ WvT, const float* __restrict__ value,
    unsigned short* __restrict__ vT,
    const float* __restrict__ enc, const unsigned short* __restrict__ WpT,
    unsigned short* __restrict__ pprj) {
    __shared__ unsigned short As[128 * 64];
    __shared__ unsigned short Bs[128 * 64];
    const int bid = blockIdx.x;
    if (bid < 128) {
        gemm_body<0, true, false>(query, WqT, bq, qprj, 512,
                                  (bid >> 2) * 128, (bid & 3) * 128, As, Bs);
    } else if (bid < 256) {
        int s = bid - 128;
        gemm_body<3, true, false>(key, WkT, nullptr, kprj, 512,
                                  (s >> 2) * 128, (s & 3) * 128, As, Bs);
    } else if (bid < 384) {
        int s = bid - 256;
        gemm_body<2, false, true>(WvT, value, nullptr, vT, 4096,
                                  (s >> 5) * 128, (s & 31) * 128, As, Bs);
    } else {
        int s = bid - 384;
        gemm_body<3, true, false>(enc, WpT, nullptr, pprj, 512,
                                  (s >> 2) * 128, (s & 3) * 128, As, Bs);
    }
}

// Output projection: ctx(bf16) @ WoT + bo -> fp32 out
__global__ __launch_bounds__(256) void gemm_out_kernel(
    const unsigned short* __restrict__ ctxbf, const unsigned short* __restrict__ WoT,
    const float* __restrict__ bo, float* __restrict__ outp) {
    __shared__ unsigned short As[128 * 64];
    __shared__ unsigned short Bs[128 * 64];
    const int bid = blockIdx.x;
    gemm_body<0, false, false>(ctxbf, WoT, bo, outp, 512,
                               (bid >> 2) * 128, (bid & 3) * 128, As, Bs);
}

// ---------------------------------------------------------------------------
// Fused attention (R12 = R9 ILP structure + head-major K/P layouts):
//   K/pos fragment loads now gather 16 CONTIGUOUS 64B rows (1KB/instr,
//   8 lines) instead of 16 rows 1KB apart (16 lines) — tests the
//   "fragment-gather transaction cost" theory for the latency floor.
// ---------------------------------------------------------------------------
__global__ __launch_bounds__(512, 4) void fused_attn_kernel(
    const float* __restrict__ qp, const unsigned short* __restrict__ kp,
    const unsigned short* __restrict__ pp, const unsigned short* __restrict__ vT,
    const float* __restrict__ ub, const float* __restrict__ vb,
    const unsigned char* __restrict__ maskb, float* __restrict__ attn,
    unsigned short* __restrict__ ctxbf) {
    // bijective XCD swizzle (4096 % 8 == 0)
    const int n = blockIdx.x + 64 * blockIdx.y + 1024 * blockIdx.z;
    const int swz = (n & 7) * 512 + (n >> 3);
    const int q0 = (swz & 63) * 16;
    const int h = (swz >> 6) & 15;
    const int b = swz >> 10;
    const int tid = threadIdx.x;
    const int w = tid >> 6, lane = tid & 63;
    const int ln = lane & 15, quad = lane >> 4;

    __shared__ __align__(16) unsigned char smem[34816];
    __shared__ float rowred[2][8][16];

    unsigned short* posb = (unsigned short*)(smem + (size_t)w * 2816); // [16][88]

    // Q row fragments
    bf16x8 a_c, a_pA, a_pB;
    {
        const float* qrow = qp + ((size_t)(b * SS + q0 + ln)) * DD + h * DH + quad * 8;
        const int qrB = q0 + ln + 1;
        const float* qrowB = qp + ((size_t)(b * SS + qrB)) * DD + h * DH + quad * 8;
#pragma unroll
        for (int j = 0; j < 8; ++j) {
            float uu = ub[h * DH + quad * 8 + j];
            float vv = vb[h * DH + quad * 8 + j];
            float qv = qrow[j];
            a_c[j] = f2bf(qv + uu);
            a_pA[j] = f2bf(qv + vv);
            a_pB[j] = (qrB < SS) ? f2bf(qrowB[j] + vv) : (short)0;
        }
    }
    // head-major bases: contiguous 64B rows
    const unsigned short* kbase = kp + (((size_t)(b * HH + h)) << 15) + quad * 8;
    const unsigned short* pbase = pp + (((size_t)h) << 15) + quad * 8;
    const int kw = w * 128;
    f32x4 acc_s[8];

    // ---- issue ALL K loads (both chunks) up front: 8 loads in flight ----
    bf16x8 bk[8];
#pragma unroll
    for (int c = 0; c < 2; ++c)
#pragma unroll
        for (int t = 0; t < 4; ++t)
            bk[c * 4 + t] = *(const bf16x8*)(
                kbase + ((kw + c * 64 + t * 16 + ln) << 5));

    // pos fragment registers, reused across chunks
    bf16x8 pA[5], pB[5];
    const int thr0 = q0 - kw + 15;
    const int thr1 = q0 - (kw + 64) + 15;
    const bool nA0 = (thr0 >= 0), nB0 = (thr0 < 78);
    const bool nA1 = (thr1 >= 0), nB1 = (thr1 < 78);

    // ---- issue chunk0 pos loads ----
    {
        const int jA0 = kw - q0 + SS - 16, jB0 = kw - q0 - 17;
#pragma unroll
        for (int t = 0; t < 5; ++t) {
            int jA = jA0 + t * 16 + ln;
            int jB = jB0 + t * 16 + ln;
#pragma unroll
            for (int jj = 0; jj < 8; ++jj) { pA[t][jj] = (short)0; pB[t][jj] = (short)0; }
            if (nA0 && (unsigned)jA < (unsigned)SS)
                pA[t] = *(const bf16x8*)(pbase + (jA << 5));
            if (nB0 && (unsigned)jB < (unsigned)SS)
                pB[t] = *(const bf16x8*)(pbase + (jB << 5));
        }
    }

    // ---- chunk0 pos MFMA + masked single-window stage ----
    if (nA0) {
#pragma unroll
        for (int t = 0; t < 5; ++t) {
            f32x4 acc = {0.f, 0.f, 0.f, 0.f};
            acc = __builtin_amdgcn_mfma_f32_16x16x32_bf16(pA[t], a_pA, acc, 0, 0, 0);
            ushort4 o;
            o.x = (unsigned short)f2bf(acc[0]); o.y = (unsigned short)f2bf(acc[1]);
            o.z = (unsigned short)f2bf(acc[2]); o.w = (unsigned short)f2bf(acc[3]);
            int p = t * 16 + quad * 4;
            if (p + 3 <= thr0) {
                *(ushort4*)(posb + ln * 88 + p) = o;
            } else if (p <= thr0) {
                const unsigned short* oe = (const unsigned short*)&o;
#pragma unroll
                for (int i = 0; i < 4; ++i)
                    if (p + i <= thr0) posb[ln * 88 + p + i] = oe[i];
            }
        }
    }
    if (nB0) {
#pragma unroll
        for (int t = 0; t < 5; ++t) {
            f32x4 acc = {0.f, 0.f, 0.f, 0.f};
            acc = __builtin_amdgcn_mfma_f32_16x16x32_bf16(pB[t], a_pB, acc, 0, 0, 0);
            ushort4 o;
            o.x = (unsigned short)f2bf(acc[0]); o.y = (unsigned short)f2bf(acc[1]);
            o.z = (unsigned short)f2bf(acc[2]); o.w = (unsigned short)f2bf(acc[3]);
            int p = t * 16 + quad * 4;
            if (p > thr0) {
                *(ushort4*)(posb + ln * 88 + p) = o;
            } else if (p + 3 > thr0) {
                const unsigned short* oe = (const unsigned short*)&o;
#pragma unroll
                for (int i = 0; i < 4; ++i)
                    if (p + i > thr0) posb[ln * 88 + p + i] = oe[i];
            }
        }
    }

    // ---- issue chunk1 pos loads (regs reused; overlap chunk0 QK below) ----
    bf16x8 pA1[5], pB1[5];
    {
        const int jA0 = (kw + 64) - q0 + SS - 16, jB0 = (kw + 64) - q0 - 17;
#pragma unroll
        for (int t = 0; t < 5; ++t) {
            int jA = jA0 + t * 16 + ln;
            int jB = jB0 + t * 16 + ln;
#pragma unroll
            for (int jj = 0; jj < 8; ++jj) { pA1[t][jj] = (short)0; pB1[t][jj] = (short)0; }
            if (nA1 && (unsigned)jA < (unsigned)SS)
                pA1[t] = *(const bf16x8*)(pbase + (jA << 5));
            if (nB1 && (unsigned)jB < (unsigned)SS)
                pB1[t] = *(const bf16x8*)(pbase + (jB << 5));
        }
    }

    // ---- chunk0 QK + pos merge (posb reads ordered before chunk1 writes) ----
#pragma unroll
    for (int t = 0; t < 4; ++t) {
        f32x4 acc = {0.f, 0.f, 0.f, 0.f};
        acc = __builtin_amdgcn_mfma_f32_16x16x32_bf16(bk[t], a_c, acc, 0, 0, 0);
#pragma unroll
        for (int r = 0; r < 4; ++r) {
            const int kkl = t * 16 + quad * 4 + r;
            acc[r] += bf2f(posb[ln * 88 + (kkl - ln + 15)]);
        }
        acc_s[t] = acc;
    }

    // ---- chunk1 pos MFMA + stage ----
    if (nA1) {
#pragma unroll
        for (int t = 0; t < 5; ++t) {
            f32x4 acc = {0.f, 0.f, 0.f, 0.f};
            acc = __builtin_amdgcn_mfma_f32_16x16x32_bf16(pA1[t], a_pA, acc, 0, 0, 0);
            ushort4 o;
            o.x = (unsigned short)f2bf(acc[0]); o.y = (unsigned short)f2bf(acc[1]);
            o.z = (unsigned short)f2bf(acc[2]); o.w = (unsigned short)f2bf(acc[3]);
            int p = t * 16 + quad * 4;
            if (p + 3 <= thr1) {
                *(ushort4*)(posb + ln * 88 + p) = o;
            } else if (p <= thr1) {
                const unsigned short* oe = (const unsigned short*)&o;
#pragma unroll
                for (int i = 0; i < 4; ++i)
                    if (p + i <= thr1) posb[ln * 88 + p + i] = oe[i];
            }
        }
    }
    if (nB1) {
#pragma unroll
        for (int t = 0; t < 5; ++t) {
            f32x4 acc = {0.f, 0.f, 0.f, 0.f};
            acc = __builtin_amdgcn_mfma_f32_16x16x32_bf16(pB1[t], a_pB, acc, 0, 0, 0);
            ushort4 o;
            o.x = (unsigned short)f2bf(acc[0]); o.y = (unsigned short)f2bf(acc[1]);
            o.z = (unsigned short)f2bf(acc[2]); o.w = (unsigned short)f2bf(acc[3]);
            int p = t * 16 + quad * 4;
            if (p > thr1) {
                *(ushort4*)(posb + ln * 88 + p) = o;
            } else if (p + 3 > thr1) {
                const unsigned short* oe = (const unsigned short*)&o;
#pragma unroll
                for (int i = 0; i < 4; ++i)
                    if (p + i > thr1) posb[ln * 88 + p + i] = oe[i];
            }
        }
    }

    // ---- chunk1 QK + pos merge ----
#pragma unroll
    for (int t = 0; t < 4; ++t) {
        f32x4 acc = {0.f, 0.f, 0.f, 0.f};
        acc = __builtin_amdgcn_mfma_f32_16x16x32_bf16(bk[4 + t], a_c, acc, 0, 0, 0);
#pragma unroll
        for (int r = 0; r < 4; ++r) {
            const int kkl = t * 16 + quad * 4 + r;
            acc[r] += bf2f(posb[ln * 88 + (kkl - ln + 15)]);
        }
        acc_s[4 + t] = acc;
    }

    // ---- phase 2: one-barrier softmax (row = ln, lane-local) ----
    const float scale = 0.04419417382415922f;   // 1/sqrt(512)
    const unsigned char* mrow = maskb + ((size_t)b << 10);
    float mx = -3.4e38f;
#pragma unroll
    for (int tt = 0; tt < 8; ++tt) {
        int col = kw + tt * 16 + quad * 4;
        uchar4 mm = *(const uchar4*)(mrow + col);
        float v0 = mm.x ? -1e9f : acc_s[tt][0] * scale;
        float v1 = mm.y ? -1e9f : acc_s[tt][1] * scale;
        float v2 = mm.z ? -1e9f : acc_s[tt][2] * scale;
        float v3 = mm.w ? -1e9f : acc_s[tt][3] * scale;
        acc_s[tt][0] = v0; acc_s[tt][1] = v1;
        acc_s[tt][2] = v2; acc_s[tt][3] = v3;
        mx = fmaxf(mx, fmaxf(fmaxf(v0, v1), fmaxf(v2, v3)));
    }
    mx = fmaxf(mx, __shfl_xor(mx, 16, 64));
    mx = fmaxf(mx, __shfl_xor(mx, 32, 64));
    float sm = 0.f;
#pragma unroll
    for (int tt = 0; tt < 8; ++tt) {
#pragma unroll
        for (int r = 0; r < 4; ++r) {
            float e = __expf(acc_s[tt][r] - mx);
            acc_s[tt][r] = e;
            sm += e;
        }
    }
    sm += __shfl_xor(sm, 16, 64);
    sm += __shfl_xor(sm, 32, 64);
    if (quad == 0) { rowred[0][w][ln] = mx; rowred[1][w][ln] = sm; }
    __syncthreads();   // single softmax barrier; posb dead from here

    // ---- issue ALL V loads: in flight under merge math + staging ----
    const size_t vbase = ((size_t)(b * HH + h)) << 15;   // *32*1024
    bf16x8 vf[8];
#pragma unroll
    for (int s = 0; s < 2; ++s)
#pragma unroll
        for (int cc = 0; cc < 2; ++cc) {
            int k0 = kw + s * 64 + cc * 32;
            vf[s * 4 + cc * 2 + 0] = *(const bf16x8*)(
                vT + vbase + (((size_t)ln) << 10) + k0 + quad * 8);
            vf[s * 4 + cc * 2 + 1] = *(const bf16x8*)(
                vT + vbase + (((size_t)(16 + ln)) << 10) + k0 + quad * 8);
        }

    float gm = -3.4e38f;
#pragma unroll
    for (int ww = 0; ww < 8; ++ww) gm = fmaxf(gm, rowred[0][ww][ln]);
    float lsum = 0.f;
#pragma unroll
    for (int ww = 0; ww < 8; ++ww)
        lsum += rowred[1][ww][ln] * __expf(rowred[0][ww][ln] - gm);
    float inv = __expf(mx - gm) / lsum;   // per-wave rescale folded in

    // ---- phase 2.5 + 3 ----
    float* stg = (float*)(smem + (size_t)w * 4352);   // [16][68] fp32
    f32x4 cacc0 = {0.f, 0.f, 0.f, 0.f}, cacc1 = {0.f, 0.f, 0.f, 0.f};
    float* abase = attn + (((size_t)(b * HH + h)) << 20) + (size_t)q0 * SS;
#pragma unroll
    for (int s = 0; s < 2; ++s) {
#pragma unroll
        for (int t = 0; t < 4; ++t) {
            int tt = s * 4 + t;
            float4 o = make_float4(acc_s[tt][0] * inv, acc_s[tt][1] * inv,
                                   acc_s[tt][2] * inv, acc_s[tt][3] * inv);
            *(float4*)&stg[ln * 68 + t * 16 + quad * 4] = o;
        }
        // full-line NT attn stores: 4 rows x 256B contiguous per instruction
#pragma unroll
        for (int i = 0; i < 4; ++i) {
            int row = i * 4 + quad;
            int c4 = ln * 4;
            f32x4 v = *(f32x4*)&stg[row * 68 + c4];
            __builtin_nontemporal_store(
                v, (f32x4*)&abase[(size_t)row * SS + kw + s * 64 + c4]);
        }
#pragma unroll
        for (int cc = 0; cc < 2; ++cc) {
            int coff = cc * 32 + quad * 8;
            float4 pa = *(float4*)&stg[ln * 68 + coff];
            float4 pb = *(float4*)&stg[ln * 68 + coff + 4];
            bf16x8 af;
            af[0] = f2bf(pa.x); af[1] = f2bf(pa.y);
            af[2] = f2bf(pa.z); af[3] = f2bf(pa.w);
            af[4] = f2bf(pb.x); af[5] = f2bf(pb.y);
            af[6] = f2bf(pb.z); af[7] = f2bf(pb.w);
            cacc0 = __builtin_amdgcn_mfma_f32_16x16x32_bf16(
                af, vf[s * 4 + cc * 2 + 0], cacc0, 0, 0, 0);
            cacc1 = __builtin_amdgcn_mfma_f32_16x16x32_bf16(
                af, vf[s * 4 + cc * 2 + 1], cacc1, 0, 0, 0);
        }
    }

    // cross-wave ctx reduce; red/ctxs alias the (dead) stg pool after barrier
    __syncthreads();
    f32x4* red = (f32x4*)smem;                              // 16384 B
    unsigned short* ctxs = (unsigned short*)(smem + 16384); // [16][32]
    red[(w * 2 + 0) * 64 + lane] = cacc0;
    red[(w * 2 + 1) * 64 + lane] = cacc1;
    __syncthreads();
    if (tid < 128) {
        int nt = tid >> 6, l2 = tid & 63;
        f32x4 s4 = {0.f, 0.f, 0.f, 0.f};
#pragma unroll
        for (int ww = 0; ww < 8; ++ww)
            s4 += red[(ww * 2 + nt) * 64 + l2];
        int qd = l2 >> 4, lc = l2 & 15;
#pragma unroll
        for (int r = 0; r < 4; ++r)
            ctxs[(qd * 4 + r) * 32 + nt * 16 + lc] = (unsigned short)f2bf(s4[r]);
    }
    __syncthreads();
    if (tid < 64) {
        int row = tid >> 2, c8 = (tid & 3) * 8;
        *(bf16x8*)(ctxbf + ((size_t)(b * SS + q0 + row)) * DD + h * DH + c8) =
            *(const bf16x8*)(ctxs + row * 32 + c8);
    }
}

// ---------------------------------------------------------------------------
extern "C" void kernel_launch(void* const* d_in, const int* in_sizes, int n_in,
                              void* d_out, int out_size, void* d_ws, size_t ws_size,
                              hipStream_t stream) {
    const float* query = (const float*)d_in[0];
    const float* key   = (const float*)d_in[1];
    const float* value = (const float*)d_in[2];
    const unsigned char* mask_raw = (const unsigned char*)d_in[3];
    const float* enc   = (const float*)d_in[4];
    const float* Wq    = (const float*)d_in[5];
    const float* bq    = (const float*)d_in[6];
    const float* Wk    = (const float*)d_in[7];
    const float* Wv    = (const float*)d_in[8];
    const float* Wp    = (const float*)d_in[9];
    const float* u_b   = (const float*)d_in[10];
    const float* v_b   = (const float*)d_in[11];
    const float* Wo    = (const float*)d_in[12];
    const float* bo    = (const float*)d_in[13];

    char* wsb = (char*)d_ws;
    float*          qprj = (float*)(wsb + 0);                     // 8 MB fp32
    unsigned short* kprj = (unsigned short*)(wsb + 8388608);      // 4 MB bf16 [b][h][s][dh]
    unsigned short* vT   = (unsigned short*)(wsb + 12582912);     // 4 MB bf16 [b][h][dh][s]
    unsigned short* pprj = (unsigned short*)(wsb + 16777216);     // 1 MB bf16 [h][s][dh]
    unsigned char*  mbyte= (unsigned char*)(wsb + 17825792);      // 4 KB
    unsigned short* ctxbf= (unsigned short*)(wsb + 17842176);     // 4 MB bf16
    unsigned short* WqT  = (unsigned short*)(wsb + 22036480);     // 512 KB
    unsigned short* WkT  = (unsigned short*)(wsb + 22560768);     // 512 KB
    unsigned short* WvT  = (unsigned short*)(wsb + 23085056);     // 512 KB
    unsigned short* WpT  = (unsigned short*)(wsb + 23609344);     // 512 KB
    unsigned short* WoT  = (unsigned short*)(wsb + 24133632);     // 512 KB

    float* outp = (float*)d_out;                 // (B,S,D)
    float* attn = outp + (size_t)BB * SS * DD;   // (B,H,S,S)

    prep_kernel<<<321, 256, 0, stream>>>(
        Wq, Wk, Wv, Wp, Wo, mask_raw, WqT, WkT, WvT, WpT, WoT, mbyte);

    gemm4_kernel<<<416, 256, 0, stream>>>(
        query, WqT, bq, qprj, key, WkT, kprj, WvT, value, vT, enc, WpT, pprj);

    fused_attn_kernel<<<dim3(SS / 16, HH, BB), 512, 0, stream>>>(
        qprj, kprj, pprj, vT, u_b, v_b, mbyte, attn, ctxbf);

    gemm_out_kernel<<<128, 256, 0, stream>>>(ctxbf, WoT, bo, outp);
}